// Round 1
// baseline (137.197 us; speedup 1.0000x reference)
//
#include <hip/hip_runtime.h>

#define HW  16384
#define WD  128

#define TS   16            // center tile side
#define HS   18            // halo side
#define HP   (HS * HS)     // 324 halo pixels
#define PRS  20            // padded halo row stride (slots)
#define PLS  360           // plane stride per c4 (ushort4 slots) = 18*20

__device__ __forceinline__ unsigned short f2bf(float f) {
    unsigned int u = __builtin_bit_cast(unsigned int, f);
    u += 0x7FFFu + ((u >> 16) & 1u);          // RNE
    return (unsigned short)(u >> 16);
}
__device__ __forceinline__ float bf2f(unsigned int s) {
    return __builtin_bit_cast(float, (s & 0xFFFFu) << 16);
}
__device__ __forceinline__ float ftanh(float v) {
    const float e = __expf(2.0f * v);
    return 1.0f - __fdividef(2.0f, e + 1.0f);
}

// conv1 (8 out x 32 in) + bn1 + tanh for t-group p. All weight/bn accesses
// are thread-uniform -> scalar loads. xv fully unrolled -> stays in VGPRs.
__device__ __forceinline__ void conv1_bn_tanh(
    const float xv[32], int p,
    const float* __restrict__ w1, const float* __restrict__ g1,
    const float* __restrict__ be1, const float* __restrict__ b1,
    const float* __restrict__ m1, const float* __restrict__ v1,
    float t[8])
{
    const float* w1g = w1 + p * 256;
#pragma unroll
    for (int o = 0; o < 8; ++o) {
        float a = 0.f;
#pragma unroll
        for (int ci = 0; ci < 32; ++ci) a = fmaf(xv[ci], w1g[o * 32 + ci], a);
        const int ch = p * 8 + o;
        const float inv = g1[ch] * rsqrtf(v1[ch] + 1e-5f);
        const float add = be1[ch] + (b1[ch] - m1[ch]) * inv;
        t[o] = ftanh(fmaf(a, inv, add));
    }
}

// ---- fully fused: one kernel, zero workspace --------------------------------
// Per (b, g, 16x16 tile) block:
//   phase 1 (halo): t0 = conv1(x grp0) -> nbs;  x grp g -> bf16 xt;  t_g -> tls
//   phase 2 (center): tA from tls, tB = conv1(x grp g+1) fp32,
//                     mask conv + softmax + x-tap accum + Wv -> out
__global__ __launch_bounds__(256, 4) void la_all(
    const float* __restrict__ x,
    const float* __restrict__ w1, const float* __restrict__ b1,
    const float* __restrict__ g1, const float* __restrict__ be1,
    const float* __restrict__ m1, const float* __restrict__ v1,
    const float* __restrict__ w2, const float* __restrict__ b2,
    const float* __restrict__ g2, const float* __restrict__ be2,
    const float* __restrict__ m2, const float* __restrict__ v2,
    const float* __restrict__ wv,
    float* __restrict__ out)
{
    __shared__ ushort4 xt[8 * PLS];   // x grp g halo, bf16x4: 23040 B
    __shared__ uint4   tls[PLS];      // t grp g halo, bf16x8:  5760 B
    __shared__ float   nbs[PLS];      // neighbor plane fp32:   1440 B

    const int tid  = threadIdx.x;
    const int bg   = blockIdx.x;
    const int tile = blockIdx.y;               // 0..63
    const int b    = bg >> 3, g = bg & 7;
    const int ty0  = (tile >> 3) * TS;
    const int tx0  = (tile & 7) * TS;

    const float* xb = x + (size_t)b * 256 * HW;          // group 0 base
    const float* xg = xb + (size_t)(g * 32) * HW;        // group g base

    // bn2 constants for neighbor channel g (conv2 group 0, out row g)
    const float inv2n = g2[g] * rsqrtf(v2[g] + 1e-5f);
    const float add2n = be2[g] + (b2[g] - m2[g]) * inv2n;

    // ---- phase 1: halo -> nbs (fp32), xt (bf16), tls (bf16) ----
    for (int hp = tid; hp < HP; hp += 256) {
        const int hy = hp / HS, hx = hp - hy * HS;
        const int iy = ty0 + hy - 1, ix = tx0 + hx - 1;
        const int slot = hy * PRS + hx;
        if (((unsigned)iy < 128u) && ((unsigned)ix < 128u)) {
            const int po = iy * WD + ix;
            float xv[32], tg[8];
            if (g == 0) {
                // group g IS group 0: one load serves nb + value + tA paths
#pragma unroll
                for (int c = 0; c < 32; ++c) xv[c] = xb[(size_t)c * HW + po];
                conv1_bn_tanh(xv, 0, w1, g1, be1, b1, m1, v1, tg);
                float an = 0.f;
#pragma unroll
                for (int i = 0; i < 8; ++i) an = fmaf(tg[i], w2[g * 8 + i], an);
                nbs[slot] = fmaf(an, inv2n, add2n);
            } else {
                {   // scoped: x0 dies before xv loads
                    float x0[32], t0[8];
#pragma unroll
                    for (int c = 0; c < 32; ++c) x0[c] = xb[(size_t)c * HW + po];
                    conv1_bn_tanh(x0, 0, w1, g1, be1, b1, m1, v1, t0);
                    float an = 0.f;
#pragma unroll
                    for (int i = 0; i < 8; ++i) an = fmaf(t0[i], w2[g * 8 + i], an);
                    nbs[slot] = fmaf(an, inv2n, add2n);
                }
#pragma unroll
                for (int c = 0; c < 32; ++c) xv[c] = xg[(size_t)c * HW + po];
                conv1_bn_tanh(xv, g, w1, g1, be1, b1, m1, v1, tg);
            }
#pragma unroll
            for (int c4 = 0; c4 < 8; ++c4)
                xt[c4 * PLS + slot] = make_ushort4(
                    f2bf(xv[c4 * 4 + 0]), f2bf(xv[c4 * 4 + 1]),
                    f2bf(xv[c4 * 4 + 2]), f2bf(xv[c4 * 4 + 3]));
            uint4 tu;
            tu.x = (unsigned)f2bf(tg[0]) | ((unsigned)f2bf(tg[1]) << 16);
            tu.y = (unsigned)f2bf(tg[2]) | ((unsigned)f2bf(tg[3]) << 16);
            tu.z = (unsigned)f2bf(tg[4]) | ((unsigned)f2bf(tg[5]) << 16);
            tu.w = (unsigned)f2bf(tg[6]) | ((unsigned)f2bf(tg[7]) << 16);
            tls[slot] = tu;
        } else {
            const ushort4 z = make_ushort4(0, 0, 0, 0);
#pragma unroll
            for (int c4 = 0; c4 < 8; ++c4) xt[c4 * PLS + slot] = z;
            tls[slot] = make_uint4(0u, 0u, 0u, 0u);
            nbs[slot] = 0.f;       // zero-padded neighbor
        }
    }
    __syncthreads();

    // ---- phase 2: one center pixel per thread ----
    const int cy  = tid >> 4, cx = tid & 15;
    const int iy  = ty0 + cy, ix = tx0 + cx;
    const int pix = iy * WD + ix;

    // mask channels mc0..mc0+8 produced by t-groups pa (k<ksplit) and pb
    const int mc0    = 8 + 9 * g;
    const int pa     = mc0 / 10;               // == g
    const int pb     = (mc0 + 8) / 10;         // == min(g+1, 7)
    const int ksplit = 10 - (mc0 - pa * 10);

    float tA[8], tB[8];
    {
        const uint4 ua = tls[(cy + 1) * PRS + (cx + 1)];
        tA[0] = bf2f(ua.x); tA[1] = bf2f(ua.x >> 16);
        tA[2] = bf2f(ua.y); tA[3] = bf2f(ua.y >> 16);
        tA[4] = bf2f(ua.z); tA[5] = bf2f(ua.z >> 16);
        tA[6] = bf2f(ua.w); tA[7] = bf2f(ua.w >> 16);
    }
    if (pb != pa) {
        float xv[32];
        const float* xn = xb + (size_t)(pb * 32) * HW + pix;
#pragma unroll
        for (int c = 0; c < 32; ++c) xv[c] = xn[(size_t)c * HW];
        conv1_bn_tanh(xv, pb, w1, g1, be1, b1, m1, v1, tB);
    } else {
#pragma unroll
        for (int o = 0; o < 8; ++o) tB[o] = tA[o];
    }

    float lg[9];
    float mx = -1e30f;
#pragma unroll
    for (int k = 0; k < 9; ++k) {
        const int mc = mc0 + k;
        const int p  = (k < ksplit) ? pa : pb;
        const int o  = mc - p * 10;
        const float* w2p = w2 + p * 80 + o * 8;
        float a = 0.f;
#pragma unroll
        for (int i = 0; i < 8; ++i) {
            const float ti = (k < ksplit) ? tA[i] : tB[i];
            a = fmaf(ti, w2p[i], a);
        }
        const float inv = g2[mc] * rsqrtf(v2[mc] + 1e-5f);
        const float add = be2[mc] + (b2[mc] - m2[mc]) * inv;
        lg[k] = fmaf(a, inv, add) + nbs[(cy + k / 3) * PRS + (cx + k % 3)];
        mx = fmaxf(mx, lg[k]);
    }
    float ssum = 0.f;
#pragma unroll
    for (int k = 0; k < 9; ++k) { lg[k] = __expf(lg[k] - mx); ssum += lg[k]; }
    const float rs = 1.f / ssum;               // applied once at the store

    // s = sum_k e_k * x_tap  (OOB taps read x==0 from LDS)
    float s[32];
#pragma unroll
    for (int c = 0; c < 32; ++c) s[c] = 0.f;
#pragma unroll
    for (int k = 0; k < 9; ++k) {
        const int slot = (cy + k / 3) * PRS + (cx + k % 3);
        const float e = lg[k];
#pragma unroll
        for (int c4 = 0; c4 < 8; ++c4) {
            const ushort4 xv4 = xt[c4 * PLS + slot];
            s[c4 * 4 + 0] = fmaf(e, bf2f(xv4.x), s[c4 * 4 + 0]);
            s[c4 * 4 + 1] = fmaf(e, bf2f(xv4.y), s[c4 * 4 + 1]);
            s[c4 * 4 + 2] = fmaf(e, bf2f(xv4.z), s[c4 * 4 + 2]);
            s[c4 * 4 + 3] = fmaf(e, bf2f(xv4.w), s[c4 * 4 + 3]);
        }
    }

    // out = rs * (Wv . s)
    const float* wvg = wv + g * 1024;
    float* og = out + (size_t)(b * 256 + g * 32) * HW + pix;
#pragma unroll 4
    for (int o = 0; o < 32; ++o) {
        const float* wp = wvg + o * 32;
        float a = 0.f;
#pragma unroll
        for (int ci = 0; ci < 32; ++ci) a = fmaf(s[ci], wp[ci], a);
        __builtin_nontemporal_store(a * rs, og + (size_t)o * HW);
    }
}

extern "C" void kernel_launch(void* const* d_in, const int* in_sizes, int n_in,
                              void* d_out, int out_size, void* d_ws, size_t ws_size,
                              hipStream_t stream)
{
    const float* x   = (const float*)d_in[0];
    const float* w1  = (const float*)d_in[1];
    const float* b1  = (const float*)d_in[2];
    const float* g1  = (const float*)d_in[3];
    const float* be1 = (const float*)d_in[4];
    const float* m1  = (const float*)d_in[5];
    const float* v1  = (const float*)d_in[6];
    const float* w2  = (const float*)d_in[7];
    const float* b2  = (const float*)d_in[8];
    const float* g2  = (const float*)d_in[9];
    const float* be2 = (const float*)d_in[10];
    const float* m2  = (const float*)d_in[11];
    const float* v2  = (const float*)d_in[12];
    const float* wv  = (const float*)d_in[13];

    float* out = (float*)d_out;
    (void)d_ws; (void)ws_size;                 // workspace unused: no poison cost

    dim3 blk(256);
    dim3 grd(16, 64);   // (bg, tile): 16 consecutive ids share a tile's grp-0 halo

    hipLaunchKernelGGL(la_all, grd, blk, 0, stream,
                       x, w1, b1, g1, be1, m1, v1, w2, b2, g2, be2, m2, v2,
                       wv, out);
}